// Round 6
// baseline (61.082 us; speedup 1.0000x reference)
//
#include <hip/hip_runtime.h>
#include <hip/hip_bf16.h>

#define NB 8
#define SEQ 2048
#define DIN 1024
#define DH 64

typedef __attribute__((ext_vector_type(8))) short bf16x8;
typedef __attribute__((ext_vector_type(4))) float f32x4;

static __device__ __forceinline__ unsigned short f2bf(float f) {
    unsigned int u = __builtin_bit_cast(unsigned int, f);
    unsigned int r = (u + 0x7FFFu + ((u >> 16) & 1u)) >> 16;
    return (unsigned short)r;
}

static __device__ __forceinline__ unsigned int cvt_pk_bf16(float lo, float hi) {
    unsigned int d;
    asm volatile("v_cvt_pk_bf16_f32 %0, %1, %2" : "=v"(d) : "v"(lo), "v"(hi));
    return d;
}

// ---------------- prep: pack W into MFMA-B-fragment-linear Wfrag.
// idx = (cg*32 + kk)*512 + cl*32 + kq*8 + ke ; col = cg*16+cl (mat=col>>6), k = kk*32+kq*8+ke
__global__ __launch_bounds__(256) void prep_kernel(
    const float* __restrict__ Wq, const float* __restrict__ Wk, const float* __restrict__ Wv,
    unsigned short* __restrict__ Wfrag)
{
    int j = blockIdx.x * 256 + threadIdx.x;     // 0 .. 196607
    int mat = j >> 16;
    int rem = j & 65535;
    int k = rem >> 6;
    int c = rem & 63;
    const float* W = (mat == 0) ? Wq : ((mat == 1) ? Wk : Wv);
    float v = W[rem];
    int col = mat * 64 + c;
    int cg = col >> 4, cl = col & 15;
    int kk = k >> 5, kq = (k >> 3) & 3, ke = k & 7;
    Wfrag[(size_t)(cg * 32 + kk) * 512 + cl * 32 + kq * 8 + ke] = f2bf(v);
}

// ---------------- QKV GEMM: BM=32, 512 blocks, dbuf LDS, 2-deep X prefetch,
// 6-slot W register pipeline (reload at c lands by c+6 ~ >=250cy cover for L2 latency).
__global__ __launch_bounds__(256, 2) void qkv_kernel(
    const float* __restrict__ X, const unsigned short* __restrict__ Wfrag,
    const float* __restrict__ bq, const float* __restrict__ bk, const float* __restrict__ bv,
    unsigned short* __restrict__ Qb, unsigned short* __restrict__ Kb, unsigned short* __restrict__ Vt)
{
    __shared__ __align__(16) short As[2][32][128];   // 16 KiB, XOR-swizzled (16B granules)

    const int tid = threadIdx.x;
    const int w   = tid >> 6;
    const int l15 = tid & 15;
    const int lq  = (tid >> 4) & 3;
    const int row0 = blockIdx.x * 32;

    f32x4 acc[2][3] = {};

    const float* xb = X + (size_t)row0 * DIN;

    const unsigned short* wfb[3];
    #pragma unroll
    for (int n = 0; n < 3; ++n)
        wfb[n] = Wfrag + (size_t)((w * 3 + n) * 32) * 512 + (l15 * 4 + lq) * 8;

    // ---- X prefetch, 2 steps deep; flat chunk c -> row c>>5, float4-col c&31
    float4 pf[2][4];
    #pragma unroll
    for (int i = 0; i < 4; ++i) {
        int c = tid + 256 * i;
        const float* p = xb + (size_t)(c >> 5) * DIN + (c & 31) * 4;
        pf[0][i] = *(const float4*)(p);
        pf[1][i] = *(const float4*)(p + 128);
    }

    // ---- W 6-slot rolling pipeline: prologue chunks 0..5
    bf16x8 wb[6][3];
    #pragma unroll
    for (int s = 0; s < 6; ++s)
        #pragma unroll
        for (int n = 0; n < 3; ++n)
            wb[s][n] = *(const bf16x8*)(wfb[n] + (size_t)s * 512);

    #pragma unroll
    for (int step = 0; step < 8; ++step) {
        const int pi = step & 1;

        unsigned int u[8];
        #pragma unroll
        for (int i = 0; i < 4; ++i) {
            u[2 * i]     = cvt_pk_bf16(pf[pi][i].x, pf[pi][i].y);
            u[2 * i + 1] = cvt_pk_bf16(pf[pi][i].z, pf[pi][i].w);
        }
        #pragma unroll
        for (int i = 0; i < 4; ++i) {
            int c = tid + 256 * i;
            int r = c >> 5;
            int bo = ((c & 31) * 8) ^ ((r & 7) << 4);
            uint2 v2; v2.x = u[2 * i]; v2.y = u[2 * i + 1];
            *(uint2*)((char*)&As[pi][r][0] + bo) = v2;
        }
        if (step + 2 < 8) {
            #pragma unroll
            for (int i = 0; i < 4; ++i) {
                int c = tid + 256 * i;
                pf[pi][i] = *(const float4*)(xb + (size_t)(c >> 5) * DIN + (step + 2) * 128 + (c & 31) * 4);
            }
        }
        __syncthreads();

        #pragma unroll
        for (int kkl = 0; kkl < 4; ++kkl) {
            const int c = step * 4 + kkl;
            bf16x8 a[2];
            #pragma unroll
            for (int m = 0; m < 2; ++m) {
                int r = m * 16 + l15;
                int bo = ((kkl * 32 + lq * 8) * 2) ^ ((r & 7) << 4);
                a[m] = *(const bf16x8*)((const char*)&As[pi][r][0] + bo);
            }
            #pragma unroll
            for (int m = 0; m < 2; ++m)
                #pragma unroll
                for (int n = 0; n < 3; ++n)
                    acc[m][n] = __builtin_amdgcn_mfma_f32_16x16x32_bf16(a[m], wb[c % 6][n], acc[m][n], 0, 0, 0);
            if (c + 6 < 32) {
                #pragma unroll
                for (int n = 0; n < 3; ++n)
                    wb[c % 6][n] = *(const bf16x8*)(wfb[n] + (size_t)(c + 6) * 512);
            }
        }
    }

    // epilogue
    #pragma unroll
    for (int n = 0; n < 3; ++n) {
        int col = w * 48 + n * 16 + l15;
        int mat = col >> 6, c = col & 63;
        float badd = ((mat == 0) ? bq : ((mat == 1) ? bk : bv))[c];
        #pragma unroll
        for (int m = 0; m < 2; ++m) {
            #pragma unroll
            for (int reg = 0; reg < 4; ++reg) {
                int row = row0 + m * 16 + lq * 4 + reg;
                unsigned short v16 = f2bf(acc[m][n][reg] + badd);
                if (mat == 0)      Qb[(size_t)row * DH + c] = v16;
                else if (mat == 1) Kb[(size_t)row * DH + c] = v16;
                else {
                    int bb = row >> 11, ss = row & 2047;
                    Vt[((size_t)(bb * DH + c)) * SEQ + ss] = v16;
                }
            }
        }
    }
}

// ---------------- flash attention (fixed-max), 4-way key split.
// block = (b, 64 q-rows, key-quarter of 512 keys); 256 thr / 4 waves; KT=64 dbuf.
// wave w: wm=w>>1 (32 q-rows), wn=w&1 (32-key half of each tile).
// Writes unnormalized partial O (fp32) + partial l to ws; merge_kernel finishes.
#define AKT 64
#define ANT 8      // 512 keys / 64
#define PP 36

__global__ __launch_bounds__(256, 3) void attn_kernel(
    const unsigned short* __restrict__ Qb, const unsigned short* __restrict__ Kb,
    const unsigned short* __restrict__ Vt, const int* __restrict__ mask,
    float* __restrict__ Opart, float* __restrict__ lpart)
{
    __shared__ __align__(16) short Ks[2][AKT][DH];   // 16 KiB, swz col^=(row&7)<<3 (shorts)
    __shared__ __align__(16) short Vs[2][DH][AKT];   // 16 KiB, [d][key], same swz
    __shared__ __align__(16) short ps[4][32][PP];    // 9 KiB per-wave P
    __shared__ float sml[4][32];

    const int tid = threadIdx.x;
    const int w   = tid >> 6;
    const int l15 = tid & 15;
    const int lq  = (tid >> 4) & 3;
    const int wm  = w >> 1;
    const int wn  = w & 1;

    int bid = blockIdx.x;
    int sbid = (bid & 7) * 128 + (bid >> 3);   // one batch per XCD
    const int b   = sbid >> 7;
    const int qt  = (sbid >> 2) & 31;
    const int kq  = sbid & 3;
    const int q0  = qt * 64;
    const int kb0 = kq * 512;

    // persistent Q fragments for this wave's 32 q-rows
    bf16x8 aq[2][2];
    #pragma unroll
    for (int m = 0; m < 2; ++m)
        #pragma unroll
        for (int kk = 0; kk < 2; ++kk)
            aq[m][kk] = *(const bf16x8*)(Qb + ((size_t)(b * SEQ + q0 + wm * 32 + m * 16 + l15)) * DH + kk * 32 + lq * 8);

    // staging maps: row = tid>>3 (0..31, +32), col = (tid&7)*8
    const int srow = tid >> 3;
    const int scol = (tid & 7) * 8;
    const int sdst = scol ^ ((srow & 7) << 3);

    const unsigned short* Kst = Kb + ((size_t)(b * SEQ) + kb0 + srow) * DH + scol;
    const unsigned short* Vst = Vt + ((size_t)(b * DH) + srow) * SEQ + kb0 + scol;

    bf16x8 kr[2], vr[2];
    #pragma unroll
    for (int i = 0; i < 2; ++i) {
        kr[i] = *(const bf16x8*)(Kst + (size_t)(i * 32) * DH);
        vr[i] = *(const bf16x8*)(Vst + (size_t)(i * 32) * SEQ);
    }

    f32x4 o[2][4];
    #pragma unroll
    for (int m = 0; m < 2; ++m)
        #pragma unroll
        for (int n = 0; n < 4; ++n) o[m][n] = f32x4{0, 0, 0, 0};
    float lr[2][4] = {};

    const float rscale = 0.022097086912079612f;  // 1/sqrt(2048)
    const int* mbase = mask + b * SEQ + kb0 + wn * 32 + l15;

    for (int t = 0; t < ANT; ++t) {
        const int cur = t & 1;

        #pragma unroll
        for (int i = 0; i < 2; ++i) *(bf16x8*)&Ks[cur][i * 32 + srow][sdst] = kr[i];
        #pragma unroll
        for (int i = 0; i < 2; ++i) *(bf16x8*)&Vs[cur][i * 32 + srow][sdst] = vr[i];

        int mk0 = mbase[t * AKT];
        int mk1 = mbase[t * AKT + 16];

        if (t + 1 < ANT) {
            #pragma unroll
            for (int i = 0; i < 2; ++i) {
                kr[i] = *(const bf16x8*)(Kst + (size_t)((t + 1) * AKT + i * 32) * DH);
                vr[i] = *(const bf16x8*)(Vst + (size_t)(i * 32) * SEQ + (t + 1) * AKT);
            }
        }

        __syncthreads();   // tile ready (dbuf: single barrier per iter is safe)

        // ---- QK^T: 32 q x 32 keys (this wave's wn-half)
        bf16x8 bkf[2][2];
        #pragma unroll
        for (int n = 0; n < 2; ++n)
            #pragma unroll
            for (int kk = 0; kk < 2; ++kk) {
                int row = wn * 32 + n * 16 + l15;
                bkf[n][kk] = *(const bf16x8*)&Ks[cur][row][(kk * 32 + lq * 8) ^ ((row & 7) << 3)];
            }
        f32x4 s[2][2];
        #pragma unroll
        for (int m = 0; m < 2; ++m)
            #pragma unroll
            for (int n = 0; n < 2; ++n) s[m][n] = f32x4{0, 0, 0, 0};
        #pragma unroll
        for (int kk = 0; kk < 2; ++kk)
            #pragma unroll
            for (int m = 0; m < 2; ++m)
                #pragma unroll
                for (int n = 0; n < 2; ++n)
                    s[m][n] = __builtin_amdgcn_mfma_f32_16x16x32_bf16(aq[m][kk], bkf[n][kk], s[m][n], 0, 0, 0);

        // ---- p = exp(s*scale + maskbias); per-lane partial l; P -> ps
        float bb0 = mk0 ? -1e30f : 0.0f;
        float bb1 = mk1 ? -1e30f : 0.0f;
        #pragma unroll
        for (int m = 0; m < 2; ++m)
            #pragma unroll
            for (int n = 0; n < 2; ++n) {
                float bvv = n ? bb1 : bb0;
                #pragma unroll
                for (int r = 0; r < 4; ++r) {
                    float p = __expf(fmaf(s[m][n][r], rscale, bvv));
                    lr[m][r] += p;
                    ps[w][m * 16 + lq * 4 + r][n * 16 + l15] = (short)f2bf(p);
                }
            }

        // ---- PV: P(32 x 32keys) x V(32keys x 64d)
        bf16x8 pa[2];
        #pragma unroll
        for (int m = 0; m < 2; ++m)
            pa[m] = *(const bf16x8*)&ps[w][m * 16 + l15][lq * 8];
        bf16x8 bvf[4];
        #pragma unroll
        for (int n = 0; n < 4; ++n) {
            int row = n * 16 + l15;
            bvf[n] = *(const bf16x8*)&Vs[cur][row][(wn * 32 + lq * 8) ^ ((row & 7) << 3)];
        }
        #pragma unroll
        for (int m = 0; m < 2; ++m)
            #pragma unroll
            for (int n = 0; n < 4; ++n)
                o[m][n] = __builtin_amdgcn_mfma_f32_16x16x32_bf16(pa[m], bvf[n], o[m][n], 0, 0, 0);
    }

    // ---- l partials: reduce over the 16 key-lanes
    #pragma unroll
    for (int off = 1; off < 16; off <<= 1)
        #pragma unroll
        for (int m = 0; m < 2; ++m)
            #pragma unroll
            for (int r = 0; r < 4; ++r) lr[m][r] += __shfl_xor(lr[m][r], off);
    if (l15 == 0) {
        #pragma unroll
        for (int m = 0; m < 2; ++m)
            #pragma unroll
            for (int r = 0; r < 4; ++r) sml[w][m * 16 + lq * 4 + r] = lr[m][r];
    }
    __syncthreads();   // all K/V reads done; overlay merge buffer on Ks/Vs

    float (*mg)[32][64] = reinterpret_cast<float (*)[32][64]>(&Ks[0][0][0]);  // 16 KiB
    if (wn == 1) {
        #pragma unroll
        for (int m = 0; m < 2; ++m)
            #pragma unroll
            for (int n = 0; n < 4; ++n)
                #pragma unroll
                for (int r = 0; r < 4; ++r)
                    mg[wm][m * 16 + lq * 4 + r][n * 16 + l15] = o[m][n][r];
    }
    __syncthreads();
    if (wn == 0) {
        #pragma unroll
        for (int m = 0; m < 2; ++m)
            #pragma unroll
            for (int n = 0; n < 4; ++n)
                #pragma unroll
                for (int r = 0; r < 4; ++r)
                    mg[wm][m * 16 + lq * 4 + r][n * 16 + l15] += o[m][n][r];
    }
    __syncthreads();

    // ---- write partial O (coalesced) and partial l
    {
        int qq = tid >> 2;            // 0..63
        int d0 = (tid & 3) * 16;      // 0,16,32,48
        float* dst = Opart + ((size_t)kq * (NB * SEQ) + b * SEQ + q0 + qq) * DH + d0;
        #pragma unroll
        for (int j = 0; j < 4; ++j)
            *(float4*)(dst + j * 4) = *(float4*)&mg[qq >> 5][qq & 31][d0 + j * 4];
    }
    if (tid < 64) {
        int wmi = tid >> 5;
        float lsum = sml[wmi * 2][tid & 31] + sml[wmi * 2 + 1][tid & 31];
        lpart[(size_t)kq * (NB * SEQ) + b * SEQ + q0 + tid] = lsum;
    }
}

// ---------------- merge: out = (sum_p Opart[p]) / (sum_p lpart[p])
__global__ __launch_bounds__(256) void merge_kernel(
    const float* __restrict__ Opart, const float* __restrict__ lpart,
    float* __restrict__ out)
{
    int bid = blockIdx.x;
    int sbid = (bid & 7) * 32 + (bid >> 3);   // match batch->XCD mapping
    int g = sbid * 256 + threadIdx.x;
    int q  = g >> 2;              // 0..16383
    int d0 = (g & 3) * 16;

    float l = lpart[q] + lpart[16384 + q] + lpart[2 * 16384 + q] + lpart[3 * 16384 + q];
    float inv = 1.0f / l;

    const float* o0 = Opart + (size_t)q * DH + d0;
    #pragma unroll
    for (int j = 0; j < 4; ++j) {
        float4 a = *(const float4*)(o0 + j * 4);
        float4 b2 = *(const float4*)(o0 + (size_t)16384 * DH + j * 4);
        float4 c = *(const float4*)(o0 + (size_t)2 * 16384 * DH + j * 4);
        float4 d = *(const float4*)(o0 + (size_t)3 * 16384 * DH + j * 4);
        float4 r;
        r.x = (a.x + b2.x + c.x + d.x) * inv;
        r.y = (a.y + b2.y + c.y + d.y) * inv;
        r.z = (a.z + b2.z + c.z + d.z) * inv;
        r.w = (a.w + b2.w + c.w + d.w) * inv;
        *(float4*)(out + (size_t)q * DH + d0 + j * 4) = r;
    }
}

extern "C" void kernel_launch(void* const* d_in, const int* in_sizes, int n_in,
                              void* d_out, int out_size, void* d_ws, size_t ws_size,
                              hipStream_t stream) {
    const float* X    = (const float*)d_in[0];
    const int*   mask = (const int*)d_in[1];
    const float* Wq   = (const float*)d_in[2];
    const float* bq   = (const float*)d_in[3];
    const float* Wk   = (const float*)d_in[4];
    const float* bk   = (const float*)d_in[5];
    const float* Wv   = (const float*)d_in[6];
    const float* bv   = (const float*)d_in[7];
    float* out = (float*)d_out;

    char* ws = (char*)d_ws;
    unsigned short* Qb    = (unsigned short*)(ws);                 // 2 MiB
    unsigned short* Kb    = (unsigned short*)(ws + (2u << 20));    // 2 MiB
    unsigned short* Vt    = (unsigned short*)(ws + (4u << 20));    // 2 MiB
    unsigned short* Wfrag = (unsigned short*)(ws + (6u << 20));    // 384 KiB
    float* Opart          = (float*)(ws + (8u << 20));             // 16 MiB
    float* lpart          = (float*)(ws + (24u << 20));            // 256 KiB

    prep_kernel<<<768, 256, 0, stream>>>(Wq, Wk, Wv, Wfrag);
    qkv_kernel<<<512, 256, 0, stream>>>(X, Wfrag, bq, bk, bv, Qb, Kb, Vt);
    attn_kernel<<<1024, 256, 0, stream>>>(Qb, Kb, Vt, mask, Opart, lpart);
    merge_kernel<<<256, 256, 0, stream>>>(Opart, lpart, out);
}